// Round 12
// baseline (206.732 us; speedup 1.0000x reference)
//
#include <hip/hip_runtime.h>
#include <hip/hip_bf16.h>

typedef unsigned short u16;
typedef __attribute__((ext_vector_type(8))) short bf16x8;
typedef __attribute__((ext_vector_type(4))) short s16x4;
typedef __attribute__((ext_vector_type(4))) float f32x4;

// Q pre-scale: 0.125 * log2(e) -> logits come out in log2 domain
#define QSCALE 0.18033688011116012f
#define RPSCALE 8.0f
#define EXP2(x) __builtin_amdgcn_exp2f(x)

__device__ __forceinline__ float bf2f(u16 u) {
  union { unsigned int i; float f; } v; v.i = ((unsigned int)u) << 16; return v.f;
}
__device__ __forceinline__ u16 f2bf(float f) {
  union { float f; unsigned int i; } v; v.f = f;
  unsigned int r = v.i + 0x7fffu + ((v.i >> 16) & 1u);
  return (u16)(r >> 16);
}
__device__ __forceinline__ unsigned int pk2bf(float a, float b) {
  union { __hip_bfloat162 h; unsigned int u; } cv;
  cv.h = __float22bfloat162_rn(float2{a, b});
  return cv.u;
}
__device__ __forceinline__ f32x4 MFMA(bf16x8 a, bf16x8 b, f32x4 c) {
  return __builtin_amdgcn_mfma_f32_16x16x32_bf16(a, b, c, 0, 0, 0);
}
__device__ __forceinline__ void cvt8(const float* p, uint4* dst) {
  float4 f0 = *(const float4*)(p);
  float4 f1 = *(const float4*)(p + 4);
  u16* t = (u16*)dst;
  t[0] = f2bf(f0.x); t[1] = f2bf(f0.y); t[2] = f2bf(f0.z); t[3] = f2bf(f0.w);
  t[4] = f2bf(f1.x); t[5] = f2bf(f1.y); t[6] = f2bf(f1.z); t[7] = f2bf(f1.w);
}
__device__ __forceinline__ void cvt8s(const float* p, uint4* dst, float s) {
  float4 f0 = *(const float4*)(p);
  float4 f1 = *(const float4*)(p + 4);
  u16* t = (u16*)dst;
  t[0] = f2bf(f0.x * s); t[1] = f2bf(f0.y * s); t[2] = f2bf(f0.z * s); t[3] = f2bf(f0.w * s);
  t[4] = f2bf(f1.x * s); t[5] = f2bf(f1.y * s); t[6] = f2bf(f1.z * s); t[7] = f2bf(f1.w * s);
}
// async global->LDS, 16B per lane; LDS dest = wave-uniform base + lane*16
__device__ __forceinline__ void gld16(const u16* g, u16* l) {
  __builtin_amdgcn_global_load_lds(
      (const __attribute__((address_space(1))) unsigned int*)g,
      (__attribute__((address_space(3))) unsigned int*)l, 16, 0, 0);
}

// ---------------------------------------------------------------------------
// One-shot fp32 -> bf16 cast of x, qkv_w, proj_w (grid covers all three).
// At HBM roofline (~6.2 TB/s measured).
// ---------------------------------------------------------------------------
#define N8_X  786432   // 8*32*32*768 / 8
#define N8_QW 221184   // 2304*768 / 8
#define N8_PW 73728    // 768*768 / 8
__global__ __launch_bounds__(256) void cast_kernel(
    const float* __restrict__ x, const float* __restrict__ qw, const float* __restrict__ pw,
    u16* __restrict__ xb, u16* __restrict__ qwb, u16* __restrict__ pwb)
{
  const int i = blockIdx.x * 256 + threadIdx.x;
  const float* s; u16* d; int off;
  if (i < N8_X)            { s = x;  d = xb;  off = i; }
  else if (i < N8_X+N8_QW) { s = qw; d = qwb; off = i - N8_X; }
  else                     { s = pw; d = pwb; off = i - (N8_X + N8_QW); }
  uint4 pk; cvt8(s + (size_t)off * 8, &pk);
  *(uint4*)(d + (size_t)off * 8) = pk;
}

// ---------------------------------------------------------------------------
// GEMM: C = A @ Bw^T + bias.  A: MxK row-major bf16, Bw: NxK row-major bf16.
// R8 structure (byte-identical arithmetic): 2-barrier loop, BK=64, LDS XOR
// slot-swizzle (bank conflicts 0, verified), gld16 staging, XCD-swizzled grid.
// BM=128, BN=NJ*32.
//
// R12 change: numerically-INERT convoy-breaking start stagger.  R11's
// K-reorder stagger gained ~3us but failed the harness post-timing accuracy
// check (accumulation-order change is not harness-safe).  Same convoy theory
// (co-resident blocks phase-lock on the shared TA/DMA pipe: all waves drain
// together -> MFMA idle, then all compute together -> TA idle; matches
// MfmaUtil 19% + VALUBusy 30% + ~50% no-pipe-busy), but de-phased purely in
// TIME: block phase p sleeps p x ~3.8K cycles before its (unchanged) K loop.
// s_sleep cannot alter results; worst case is a bounded ~1.5-3us tail cost.
// QKV: NJ=6, PH=3 (3 blocks/CU), grid 64x12 = 768, zero tail.
// proj: NJ=3, PH=2 (2 blocks/CU), grid 64x8 = 512, zero tail.
// MODE 0: plain row-major fp32 C0[m*N+n]
// MODE 1: QKV scatter: n -> (which, head, c); m -> (b, npos)
//   which 0 -> Q[bh][npos][c] bf16, PRE-SCALED by QSCALE
//   which 1 -> K fragment-linear: [bh][kt][mk][half][lane][8]
//   which 2 -> V fragment-linear: [bh][kt][ks][nd][lane][8]
// ---------------------------------------------------------------------------
template<int MODE, int NXB, int NJ, int PH>
__global__ __launch_bounds__(256) void gemm_bt(
    const u16* __restrict__ A, const u16* __restrict__ Bw, const float* __restrict__ bias,
    void* __restrict__ C0v, u16* __restrict__ C1, u16* __restrict__ C2,
    int M, int N, int K)
{
  __shared__ u16 sA[128 * 64];        // [row][64], slot-swizzled
  __shared__ u16 sB[NJ * 32 * 64];
  const int tid = threadIdx.x;
  const int lane = tid & 63, wv = tid >> 6;
  const int wr = wv >> 1, wc = wv & 1;
  const int l16 = lane & 15, quad = lane >> 4;
  // XCD swizzle: my ≡ bi (mod 8)
  const int bi = blockIdx.x;
  const int t0_ = bi >> 3;
  const int nx = t0_ % NXB;
  const int my = ((t0_ / NXB) << 3) | (bi & 7);
  const int m0 = my << 7, n0 = nx * (NJ * 32);

  // staging: round r covers rows r*32 + (tid>>3); LDS slot tid&7 holds
  // global col8 = (tid&7) ^ (row&7)  (inverse swizzle on the source)
  const int rs = tid >> 3;                               // 0..31
  const int gsl = (((tid & 7) ^ (rs & 7)) << 3);         // global col offset
  const int wch = wv << 9;                               // dest: wave chunk (512 elems)
  const u16* gA0 = A  + (size_t)(m0 + rs) * K + gsl;
  const u16* gB0 = Bw + (size_t)(n0 + rs) * K + gsl;

#define STAGE(k0) do { \
    _Pragma("unroll") \
    for (int r_ = 0; r_ < 4; ++r_) \
      gld16(gA0 + (size_t)r_ * 32 * K + (k0), sA + r_ * 2048 + wch); \
    _Pragma("unroll") \
    for (int r_ = 0; r_ < NJ; ++r_) \
      gld16(gB0 + (size_t)r_ * 32 * K + (k0), sB + r_ * 2048 + wch); \
  } while (0)

  // swizzled ds_read slot offsets for k-halves 0/1: slot = (h*4+quad)^(row&7)
  const int s7 = l16 & 7;
  const int sl[2] = { ((quad ^ s7) << 3), (((4 + quad) ^ s7) << 3) };

  // R12: time-only convoy-breaking stagger (no arithmetic change).
  // phase key separates both {bi,bi+256,bi+512} (XCD round-robin
  // co-residency) and {bi,bi+1,bi+2} (linear).  ~3.8K cy per phase unit
  // vs ~11K cy per K-step.
  {
    const int phase = ((bi >> 8) + bi) % PH;
    for (int i = 0; i < phase * 60; ++i) __builtin_amdgcn_s_sleep(1);
  }

  f32x4 acc[4][NJ];
  #pragma unroll
  for (int i = 0; i < 4; ++i)
    #pragma unroll
    for (int j = 0; j < NJ; ++j) {
      acc[i][j][0] = 0.f; acc[i][j][1] = 0.f; acc[i][j][2] = 0.f; acc[i][j][3] = 0.f;
    }

  const int NT = K >> 6;     // 12 for K=768
  #pragma unroll 1
  for (int t = 0; t < NT; ++t) {
    __syncthreads();                 // WAR: prior tile's reads complete
    STAGE(t << 6);
    __syncthreads();                 // drains vmcnt -> tile ready
    #pragma unroll
    for (int h = 0; h < 2; ++h) {
      bf16x8 af[4], bfr[NJ];
      #pragma unroll
      for (int i = 0; i < 4; ++i)
        af[i] = *(const bf16x8*)(sA + (wr * 64 + i * 16 + l16) * 64 + sl[h]);
      #pragma unroll
      for (int j = 0; j < NJ; ++j)
        bfr[j] = *(const bf16x8*)(sB + (wc * (NJ * 16) + j * 16 + l16) * 64 + sl[h]);
      #pragma unroll
      for (int i = 0; i < 4; ++i)
        #pragma unroll
        for (int j = 0; j < NJ; ++j)
          acc[i][j] = MFMA(af[i], bfr[j], acc[i][j]);
    }
  }
#undef STAGE

  #pragma unroll
  for (int j = 0; j < NJ; ++j) {
    const int n = n0 + wc * (NJ * 16) + j * 16 + l16;
    const float bv = bias[n];
    if (MODE == 0) {
      float* C0 = (float*)C0v;
      #pragma unroll
      for (int i = 0; i < 4; ++i) {
        const int m = m0 + wr * 64 + i * 16 + quad * 4;
        #pragma unroll
        for (int r = 0; r < 4; ++r)
          C0[(size_t)(m + r) * N + n] = acc[i][j][r] + bv;
      }
    } else {
      u16* C0 = (u16*)C0v;
      const int which = n / 768;            // uniform per 16-lane span
      const int rem = n - which * 768;
      const int head = rem >> 6, c = rem & 63;
      #pragma unroll
      for (int i = 0; i < 4; ++i) {
        const int m = m0 + wr * 64 + i * 16 + quad * 4;
        const int b = m >> 10, npos = m & 1023;
        const size_t bh = (size_t)(b * 12 + head);
        if (which == 0) {
          #pragma unroll
          for (int r = 0; r < 4; ++r)
            C0[(bh << 16) + ((size_t)(npos + r) << 6) + c] =
                f2bf((acc[i][j][r] + bv) * QSCALE);
        } else if (which == 1) {
          const size_t base = ((bh * 16 + (size_t)(npos >> 6)) << 12)
                            + (size_t)((((npos >> 4) & 3) * 2 + (c >> 5)) << 9)
                            + (size_t)((((npos & 15) + 16 * ((c >> 3) & 3)) << 3) + (c & 7));
          #pragma unroll
          for (int r = 0; r < 4; ++r)
            C1[base + r * 8] = f2bf(acc[i][j][r] + bv);
        } else {
          const size_t base = ((bh * 16 + (size_t)(npos >> 6)) << 12)
                            + (size_t)(((((npos >> 5) & 1) * 4 + (c >> 4))) << 9)
                            + (size_t)((((c & 15) + 16 * ((npos >> 3) & 3)) << 3) + (npos & 7));
          s16x4 pk;
          #pragma unroll
          for (int r = 0; r < 4; ++r) pk[r] = (short)f2bf(acc[i][j][r] + bv);
          *(s16x4*)(C2 + base) = pk;   // npos&7 in {0,4} -> 8B aligned
        }
      }
    }
  }
}

// ---------------------------------------------------------------------------
// Attention (R2/R8 best-measured version): 128 q-rows per block (32 per wave,
// two 16-row q-tiles), grid 96x8 = 768 blocks -> 3 blocks/CU.  Barrier-free
// main loop, fragment-linear K/V direct from global (L2-hot via XCD swizzle;
// LDS staging of L2-fit data measured regression R7; setprio measured null
// R9), log2-domain softmax, wave-private P buffer, O^T = V^T.P^T epilogue.
// ---------------------------------------------------------------------------
__global__ __launch_bounds__(256) void attn_kernel(
    const u16* __restrict__ Q, const u16* __restrict__ Kf, const u16* __restrict__ Vf,
    const float* __restrict__ rph, const float* __restrict__ rpw,
    u16* __restrict__ Oa)
{
  __shared__ __align__(16) u16 uni[9216];
  __shared__ u16 sSh[4 * 32 * 36];

  u16* const uRPH = uni;            // 63 rows x stride 72
  u16* const uRPW = uni + 4536;     // 64 rows x stride 72 (row 63 zero)

  const int tid = threadIdx.x;
  const int wave = tid >> 6, lane = tid & 63;
  const int l16 = lane & 15, quad = lane >> 4;
  const int bi = blockIdx.x;
  const int t = bi >> 3;
  const int qb = t & 7;                          // q-block 0..7 (128 rows each)
  const int bh = ((t >> 3) << 3) | (bi & 7);     // 0..95
  const int qrow0 = (qb << 7) + (wave << 5);     // this wave's 32 q rows
  const int qh = qrow0 >> 5;                     // wave-uniform (32 | qrow0)

  u16* const pw = uni + wave * 2304;   // wave-private P / Sw scratch (32 x 72)
  u16* const sShw = sSh + wave * 1152; // wave-private Sh (32 x 36)

  bf16x8 qf[2][2];
  #pragma unroll
  for (int qt = 0; qt < 2; ++qt) {
    const u16* qp = Q + (((size_t)bh << 10) + qrow0 + qt * 16 + l16) * 64 + quad * 8;
    qf[qt][0] = *(const bf16x8*)(qp);
    qf[qt][1] = *(const bf16x8*)(qp + 32);
  }

  // ---- stage rel-pos tables (fp32 -> bf16, x8 scale, log2 domain) ----
  for (int j = tid; j < 64 * 8; j += 256) {
    const int row = j >> 3, ck = (j & 7) << 3;
    uint4 vw;
    if (row < 63) cvt8s(rpw + (size_t)row * 64 + ck, &vw, RPSCALE);
    else { vw.x = 0u; vw.y = 0u; vw.z = 0u; vw.w = 0u; }
    *(uint4*)(uRPW + row * 72 + ck) = vw;
    if (row < 63) {
      uint4 vh;
      cvt8s(rph + (size_t)row * 64 + ck, &vh, RPSCALE);
      *(uint4*)(uRPH + row * 72 + ck) = vh;
    }
  }
  __syncthreads();

  // ---- Sh[q][kh] = Qs·rp8h[qh+31-kh] -> sShw (32 x 36) ----
  #pragma unroll
  for (int qt = 0; qt < 2; ++qt)
    #pragma unroll
    for (int tk = 0; tk < 2; ++tk) {
      const int kh = tk * 16 + l16;
      const u16* bp = uRPH + (qh + 31 - kh) * 72 + quad * 8;
      bf16x8 b0 = *(const bf16x8*)(bp);
      bf16x8 b1 = *(const bf16x8*)(bp + 32);
      f32x4 c; c[0] = 0.f; c[1] = 0.f; c[2] = 0.f; c[3] = 0.f;
      c = MFMA(qf[qt][0], b0, c);
      c = MFMA(qf[qt][1], b1, c);
      #pragma unroll
      for (int r = 0; r < 4; ++r)
        sShw[(qt * 16 + quad * 4 + r) * 36 + tk * 16 + l16] = f2bf(c[r]);
    }

  // ---- Sw[q][j] = Qs·rp8w[j]; held in regs until barrier ----
  f32x4 swc[2][4];
  #pragma unroll
  for (int qt = 0; qt < 2; ++qt)
    #pragma unroll
    for (int tj = 0; tj < 4; ++tj) {
      const u16* bp = uRPW + (tj * 16 + l16) * 72 + quad * 8;
      bf16x8 b0 = *(const bf16x8*)(bp);
      bf16x8 b1 = *(const bf16x8*)(bp + 32);
      f32x4 c; c[0] = 0.f; c[1] = 0.f; c[2] = 0.f; c[3] = 0.f;
      c = MFMA(qf[qt][0], b0, c);
      c = MFMA(qf[qt][1], b1, c);
      swc[qt][tj] = c;
    }
  __syncthreads();   // all uRPH/uRPW reads complete before pw overwrites

  #pragma unroll
  for (int qt = 0; qt < 2; ++qt)
    #pragma unroll
    for (int tj = 0; tj < 4; ++tj)
      #pragma unroll
      for (int r = 0; r < 4; ++r)
        pw[(qt * 16 + quad * 4 + r) * 72 + tj * 16 + l16] = f2bf(swc[qt][tj][r]);

  // gather rel_w[qw][kw] = Sw[q][qw-kw+31] (wave-private, in-order RAW)
  float rw[2][2][4];
  #pragma unroll
  for (int qt = 0; qt < 2; ++qt)
    #pragma unroll
    for (int hi = 0; hi < 2; ++hi)
      #pragma unroll
      for (int r = 0; r < 4; ++r) {
        const int kw = hi * 16 + quad * 4 + r;
        rw[qt][hi][r] = bf2f(pw[(qt * 16 + l16) * 72 + (qt * 16 + l16 - kw + 31)]);
      }

  f32x4 oacc[2][4];
  #pragma unroll
  for (int qt = 0; qt < 2; ++qt)
    #pragma unroll
    for (int nd = 0; nd < 4; ++nd) {
      oacc[qt][nd][0] = 0.f; oacc[qt][nd][1] = 0.f;
      oacc[qt][nd][2] = 0.f; oacc[qt][nd][3] = 0.f;
    }
  float lsum[2] = {0.f, 0.f};

  const u16* const Kfb = Kf + (((size_t)bh) << 16) + lane * 8;
  const u16* const Vfb = Vf + (((size_t)bh) << 16) + lane * 8;

  for (int kt = 0; kt < 16; ++kt) {
    const u16* Kp = Kfb + ((size_t)kt << 12);
    const u16* Vp = Vfb + ((size_t)kt << 12);
    bf16x8 kfr[8];
    #pragma unroll
    for (int m = 0; m < 8; ++m)
      kfr[m] = *(const bf16x8*)(Kp + (m << 9));
    #pragma unroll
    for (int m = 0; m < 8; ++m)
      asm volatile("" :: "v"(kfr[m]));

    float rh[2][2];
    #pragma unroll
    for (int qt = 0; qt < 2; ++qt) {
      const unsigned int w2 =
          *(const unsigned int*)(sShw + (qt * 16 + l16) * 36 + (kt << 1));
      rh[qt][0] = bf2f((u16)(w2 & 0xffffu));
      rh[qt][1] = bf2f((u16)(w2 >> 16));
    }

    #pragma unroll
    for (int qt = 0; qt < 2; ++qt) {
      f32x4 sacc[4];
      #pragma unroll
      for (int mk = 0; mk < 4; ++mk) {
        f32x4 t4; t4[0] = 0.f; t4[1] = 0.f; t4[2] = 0.f; t4[3] = 0.f;
        t4 = MFMA(kfr[mk * 2 + 0], qf[qt][0], t4);
        t4 = MFMA(kfr[mk * 2 + 1], qf[qt][1], t4);
        sacc[mk] = t4;
      }
      #pragma unroll
      for (int mk = 0; mk < 4; ++mk) {
        const float rhv = rh[qt][mk >> 1];
        const float* rwp = rw[qt][mk & 1];
        float e0 = EXP2(sacc[mk][0] + rhv + rwp[0]);
        float e1 = EXP2(sacc[mk][1] + rhv + rwp[1]);
        float e2 = EXP2(sacc[mk][2] + rhv + rwp[2]);
        float e3 = EXP2(sacc[mk][3] + rhv + rwp[3]);
        lsum[qt] += (e0 + e1) + (e2 + e3);
        uint2 pk2; pk2.x = pk2bf(e0, e1); pk2.y = pk2bf(e2, e3);
        *(uint2*)(pw + (qt * 16 + l16) * 72 + mk * 16 + quad * 4) = pk2;
      }
    }

    #pragma unroll
    for (int ks = 0; ks < 2; ++ks) {
      bf16x8 bv[4];
      #pragma unroll
      for (int nd = 0; nd < 4; ++nd)
        bv[nd] = *(const bf16x8*)(Vp + ((ks * 4 + nd) << 9));
      #pragma unroll
      for (int qt = 0; qt < 2; ++qt) {
        bf16x8 ap = *(const bf16x8*)(pw + (qt * 16 + l16) * 72 + ks * 32 + quad * 8);
        #pragma unroll
        for (int nd = 0; nd < 4; ++nd)
          oacc[qt][nd] = MFMA(bv[nd], ap, oacc[qt][nd]);
      }
    }
  }

  const int b = bh / 12, head = bh - b * 12;
  #pragma unroll
  for (int qt = 0; qt < 2; ++qt) {
    float ls = lsum[qt];
    ls += __shfl_xor(ls, 16);
    ls += __shfl_xor(ls, 32);
    const float linv = 1.0f / ls;
    const size_t base =
        ((size_t)(b << 10) + qrow0 + qt * 16 + l16) * 768 + head * 64 + quad * 4;
    #pragma unroll
    for (int nd = 0; nd < 4; ++nd) {
      s16x4 pk;
      #pragma unroll
      for (int r = 0; r < 4; ++r) pk[r] = (short)f2bf(oacc[qt][nd][r] * linv);
      *(s16x4*)(Oa + base + nd * 16) = pk;
    }
  }
}

// ---------------------------------------------------------------------------
extern "C" void kernel_launch(void* const* d_in, const int* in_sizes, int n_in,
                              void* d_out, int out_size, void* d_ws, size_t ws_size,
                              hipStream_t stream) {
  (void)in_sizes; (void)n_in; (void)out_size; (void)ws_size;
  const float* x      = (const float*)d_in[0];   // (8,32,32,768)
  const float* qkv_w  = (const float*)d_in[1];   // (2304,768)
  const float* qkv_b  = (const float*)d_in[2];   // (2304)
  const float* proj_w = (const float*)d_in[3];   // (768,768)
  const float* proj_b = (const float*)d_in[4];   // (768)
  const float* rph    = (const float*)d_in[5];   // (63,64)
  const float* rpw    = (const float*)d_in[6];   // (63,64)
  float* out = (float*)d_out;

  char* ws = (char*)d_ws;
  const size_t SZ = (size_t)96 * 1024 * 64;     // elems per plane (12 MB)
  u16* Qw  = (u16*)ws;                          // Qs [bh][n][c] bf16 (pre-scaled)
  u16* Kfw = Qw + SZ;                           // K  fragment-linear bf16
  u16* Vfw = Kfw + SZ;                          // V  fragment-linear bf16
  u16* Xb  = Vfw + SZ;                          // bf16 x; aliased as Oa after QKV GEMM
  u16* Oa  = Xb;                                //   (x dead once QKV GEMM completes)
  u16* QWb = Xb + SZ;                           // bf16 qkv_w (2304x768)
  u16* PWb = QWb + (size_t)2304 * 768;          // bf16 proj_w (768x768)  -> ~55 MB total

  cast_kernel<<<4224, 256, 0, stream>>>(x, qkv_w, proj_w, Xb, QWb, PWb);
  // QKV: BM=128, BN=192 (NJ=6), grid 64x12 = 768 = 3 blocks/CU; PH=3 sleep-stagger
  gemm_bt<1, 12, 6, 3><<<768, 256, 0, stream>>>(Xb, QWb, qkv_b, Qw, Kfw, Vfw, 8192, 2304, 768);
  attn_kernel<<<768, 256, 0, stream>>>(Qw, Kfw, Vfw, rph, rpw, Oa);
  // proj: BM=128, BN=96 (NJ=3), grid 64x8 = 512 = 2 blocks/CU; PH=2 sleep-stagger
  gemm_bt<0, 8, 3, 2><<<512, 256, 0, stream>>>(Oa, PWb, proj_b, out, nullptr, nullptr, 8192, 768, 768);
}

// Round 13
// 201.685 us; speedup vs baseline: 1.0250x; 1.0250x over previous
//
#include <hip/hip_runtime.h>
#include <hip/hip_bf16.h>

typedef unsigned short u16;
typedef __attribute__((ext_vector_type(8))) short bf16x8;
typedef __attribute__((ext_vector_type(4))) short s16x4;
typedef __attribute__((ext_vector_type(4))) float f32x4;

// Q pre-scale: 0.125 * log2(e) -> logits come out in log2 domain
#define QSCALE 0.18033688011116012f
#define RPSCALE 8.0f
#define EXP2(x) __builtin_amdgcn_exp2f(x)

__device__ __forceinline__ float bf2f(u16 u) {
  union { unsigned int i; float f; } v; v.i = ((unsigned int)u) << 16; return v.f;
}
__device__ __forceinline__ u16 f2bf(float f) {
  union { float f; unsigned int i; } v; v.f = f;
  unsigned int r = v.i + 0x7fffu + ((v.i >> 16) & 1u);
  return (u16)(r >> 16);
}
__device__ __forceinline__ unsigned int pk2bf(float a, float b) {
  union { __hip_bfloat162 h; unsigned int u; } cv;
  cv.h = __float22bfloat162_rn(float2{a, b});
  return cv.u;
}
__device__ __forceinline__ f32x4 MFMA(bf16x8 a, bf16x8 b, f32x4 c) {
  return __builtin_amdgcn_mfma_f32_16x16x32_bf16(a, b, c, 0, 0, 0);
}
__device__ __forceinline__ void cvt8(const float* p, uint4* dst) {
  float4 f0 = *(const float4*)(p);
  float4 f1 = *(const float4*)(p + 4);
  u16* t = (u16*)dst;
  t[0] = f2bf(f0.x); t[1] = f2bf(f0.y); t[2] = f2bf(f0.z); t[3] = f2bf(f0.w);
  t[4] = f2bf(f1.x); t[5] = f2bf(f1.y); t[6] = f2bf(f1.z); t[7] = f2bf(f1.w);
}
__device__ __forceinline__ void cvt8s(const float* p, uint4* dst, float s) {
  float4 f0 = *(const float4*)(p);
  float4 f1 = *(const float4*)(p + 4);
  u16* t = (u16*)dst;
  t[0] = f2bf(f0.x * s); t[1] = f2bf(f0.y * s); t[2] = f2bf(f0.z * s); t[3] = f2bf(f0.w * s);
  t[4] = f2bf(f1.x * s); t[5] = f2bf(f1.y * s); t[6] = f2bf(f1.z * s); t[7] = f2bf(f1.w * s);
}
// async global->LDS, 16B per lane; LDS dest = wave-uniform base + lane*16
__device__ __forceinline__ void gld16(const u16* g, u16* l) {
  __builtin_amdgcn_global_load_lds(
      (const __attribute__((address_space(1))) unsigned int*)g,
      (__attribute__((address_space(3))) unsigned int*)l, 16, 0, 0);
}

// ---------------------------------------------------------------------------
// One-shot fp32 -> bf16 cast of x, qkv_w, proj_w (grid covers all three).
// At HBM roofline (~6.2 TB/s measured).
// ---------------------------------------------------------------------------
#define N8_X  786432   // 8*32*32*768 / 8
#define N8_QW 221184   // 2304*768 / 8
#define N8_PW 73728    // 768*768 / 8
__global__ __launch_bounds__(256) void cast_kernel(
    const float* __restrict__ x, const float* __restrict__ qw, const float* __restrict__ pw,
    u16* __restrict__ xb, u16* __restrict__ qwb, u16* __restrict__ pwb)
{
  const int i = blockIdx.x * 256 + threadIdx.x;
  const float* s; u16* d; int off;
  if (i < N8_X)            { s = x;  d = xb;  off = i; }
  else if (i < N8_X+N8_QW) { s = qw; d = qwb; off = i - N8_X; }
  else                     { s = pw; d = pwb; off = i - (N8_X + N8_QW); }
  uint4 pk; cvt8(s + (size_t)off * 8, &pk);
  *(uint4*)(d + (size_t)off * 8) = pk;
}

// ---------------------------------------------------------------------------
// GEMM: C = A @ Bw^T + bias.  A: MxK row-major bf16, Bw: NxK row-major bf16.
// Best-measured config (R8, 203.5 us total): 2-barrier loop, BK=64, LDS XOR
// slot-swizzle (bank conflicts = 0, verified), gld16 staging, XCD-swizzled
// grid.  BM=128, BN=NJ*32.
// QKV: NJ=6 (BN=192), grid 64x12 = 768 = exactly 3 blocks/CU, zero tail.
// proj: NJ=3 (BN=96),  grid 64x8  = 512 = exactly 2 blocks/CU, zero tail.
// Session A/B record on this kernel: 8-phase schedules regressed (R3/R4),
// counted-vmcnt triple-buffer regressed (R5), K-reorder stagger not
// harness-safe (R11), sleep stagger null (R12).
// MODE 0: plain row-major fp32 C0[m*N+n]
// MODE 1: QKV scatter: n -> (which, head, c); m -> (b, npos)
//   which 0 -> Q[bh][npos][c] bf16, PRE-SCALED by QSCALE
//   which 1 -> K fragment-linear: [bh][kt][mk][half][lane][8]
//   which 2 -> V fragment-linear: [bh][kt][ks][nd][lane][8]
// ---------------------------------------------------------------------------
template<int MODE, int NXB, int NJ>
__global__ __launch_bounds__(256) void gemm_bt(
    const u16* __restrict__ A, const u16* __restrict__ Bw, const float* __restrict__ bias,
    void* __restrict__ C0v, u16* __restrict__ C1, u16* __restrict__ C2,
    int M, int N, int K)
{
  __shared__ u16 sA[128 * 64];        // [row][64], slot-swizzled
  __shared__ u16 sB[NJ * 32 * 64];
  const int tid = threadIdx.x;
  const int lane = tid & 63, wv = tid >> 6;
  const int wr = wv >> 1, wc = wv & 1;
  const int l16 = lane & 15, quad = lane >> 4;
  // XCD swizzle: my ≡ bi (mod 8)
  const int bi = blockIdx.x;
  const int t0_ = bi >> 3;
  const int nx = t0_ % NXB;
  const int my = ((t0_ / NXB) << 3) | (bi & 7);
  const int m0 = my << 7, n0 = nx * (NJ * 32);

  // staging: round r covers rows r*32 + (tid>>3); LDS slot tid&7 holds
  // global col8 = (tid&7) ^ (row&7)  (inverse swizzle on the source)
  const int rs = tid >> 3;                               // 0..31
  const int gsl = (((tid & 7) ^ (rs & 7)) << 3);         // global col offset
  const int wch = wv << 9;                               // dest: wave chunk (512 elems)
  const u16* gA0 = A  + (size_t)(m0 + rs) * K + gsl;
  const u16* gB0 = Bw + (size_t)(n0 + rs) * K + gsl;

#define STAGE(k0) do { \
    _Pragma("unroll") \
    for (int r_ = 0; r_ < 4; ++r_) \
      gld16(gA0 + (size_t)r_ * 32 * K + (k0), sA + r_ * 2048 + wch); \
    _Pragma("unroll") \
    for (int r_ = 0; r_ < NJ; ++r_) \
      gld16(gB0 + (size_t)r_ * 32 * K + (k0), sB + r_ * 2048 + wch); \
  } while (0)

  // swizzled ds_read slot offsets for k-halves 0/1: slot = (h*4+quad)^(row&7)
  const int s7 = l16 & 7;
  const int sl[2] = { ((quad ^ s7) << 3), (((4 + quad) ^ s7) << 3) };

  f32x4 acc[4][NJ];
  #pragma unroll
  for (int i = 0; i < 4; ++i)
    #pragma unroll
    for (int j = 0; j < NJ; ++j) {
      acc[i][j][0] = 0.f; acc[i][j][1] = 0.f; acc[i][j][2] = 0.f; acc[i][j][3] = 0.f;
    }

  const int NT = K >> 6;     // 12 for K=768
  #pragma unroll 1
  for (int t = 0; t < NT; ++t) {
    __syncthreads();                 // WAR: prior tile's reads complete
    STAGE(t << 6);
    __syncthreads();                 // drains vmcnt -> tile ready
    #pragma unroll
    for (int h = 0; h < 2; ++h) {
      bf16x8 af[4], bfr[NJ];
      #pragma unroll
      for (int i = 0; i < 4; ++i)
        af[i] = *(const bf16x8*)(sA + (wr * 64 + i * 16 + l16) * 64 + sl[h]);
      #pragma unroll
      for (int j = 0; j < NJ; ++j)
        bfr[j] = *(const bf16x8*)(sB + (wc * (NJ * 16) + j * 16 + l16) * 64 + sl[h]);
      #pragma unroll
      for (int i = 0; i < 4; ++i)
        #pragma unroll
        for (int j = 0; j < NJ; ++j)
          acc[i][j] = MFMA(af[i], bfr[j], acc[i][j]);
    }
  }
#undef STAGE

  #pragma unroll
  for (int j = 0; j < NJ; ++j) {
    const int n = n0 + wc * (NJ * 16) + j * 16 + l16;
    const float bv = bias[n];
    if (MODE == 0) {
      float* C0 = (float*)C0v;
      #pragma unroll
      for (int i = 0; i < 4; ++i) {
        const int m = m0 + wr * 64 + i * 16 + quad * 4;
        #pragma unroll
        for (int r = 0; r < 4; ++r)
          C0[(size_t)(m + r) * N + n] = acc[i][j][r] + bv;
      }
    } else {
      u16* C0 = (u16*)C0v;
      const int which = n / 768;            // uniform per 16-lane span
      const int rem = n - which * 768;
      const int head = rem >> 6, c = rem & 63;
      #pragma unroll
      for (int i = 0; i < 4; ++i) {
        const int m = m0 + wr * 64 + i * 16 + quad * 4;
        const int b = m >> 10, npos = m & 1023;
        const size_t bh = (size_t)(b * 12 + head);
        if (which == 0) {
          #pragma unroll
          for (int r = 0; r < 4; ++r)
            C0[(bh << 16) + ((size_t)(npos + r) << 6) + c] =
                f2bf((acc[i][j][r] + bv) * QSCALE);
        } else if (which == 1) {
          const size_t base = ((bh * 16 + (size_t)(npos >> 6)) << 12)
                            + (size_t)((((npos >> 4) & 3) * 2 + (c >> 5)) << 9)
                            + (size_t)((((npos & 15) + 16 * ((c >> 3) & 3)) << 3) + (c & 7));
          #pragma unroll
          for (int r = 0; r < 4; ++r)
            C1[base + r * 8] = f2bf(acc[i][j][r] + bv);
        } else {
          const size_t base = ((bh * 16 + (size_t)(npos >> 6)) << 12)
                            + (size_t)(((((npos >> 5) & 1) * 4 + (c >> 4))) << 9)
                            + (size_t)((((c & 15) + 16 * ((npos >> 3) & 3)) << 3) + (npos & 7));
          s16x4 pk;
          #pragma unroll
          for (int r = 0; r < 4; ++r) pk[r] = (short)f2bf(acc[i][j][r] + bv);
          *(s16x4*)(C2 + base) = pk;   // npos&7 in {0,4} -> 8B aligned
        }
      }
    }
  }
}

// ---------------------------------------------------------------------------
// Attention (best-measured version): 128 q-rows per block (32 per wave, two
// 16-row q-tiles), grid 96x8 = 768 blocks -> 3 blocks/CU.  Barrier-free main
// loop, fragment-linear K/V direct from global (L2-hot via XCD swizzle; LDS
// staging of L2-fit data measured regression R7; setprio measured null R9),
// log2-domain softmax (Q pre-scaled, v_exp_f32), wave-private P buffer,
// O^T = V^T.P^T epilogue.
// ---------------------------------------------------------------------------
__global__ __launch_bounds__(256) void attn_kernel(
    const u16* __restrict__ Q, const u16* __restrict__ Kf, const u16* __restrict__ Vf,
    const float* __restrict__ rph, const float* __restrict__ rpw,
    u16* __restrict__ Oa)
{
  __shared__ __align__(16) u16 uni[9216];
  __shared__ u16 sSh[4 * 32 * 36];

  u16* const uRPH = uni;            // 63 rows x stride 72
  u16* const uRPW = uni + 4536;     // 64 rows x stride 72 (row 63 zero)

  const int tid = threadIdx.x;
  const int wave = tid >> 6, lane = tid & 63;
  const int l16 = lane & 15, quad = lane >> 4;
  const int bi = blockIdx.x;
  const int t = bi >> 3;
  const int qb = t & 7;                          // q-block 0..7 (128 rows each)
  const int bh = ((t >> 3) << 3) | (bi & 7);     // 0..95
  const int qrow0 = (qb << 7) + (wave << 5);     // this wave's 32 q rows
  const int qh = qrow0 >> 5;                     // wave-uniform (32 | qrow0)

  u16* const pw = uni + wave * 2304;   // wave-private P / Sw scratch (32 x 72)
  u16* const sShw = sSh + wave * 1152; // wave-private Sh (32 x 36)

  bf16x8 qf[2][2];
  #pragma unroll
  for (int qt = 0; qt < 2; ++qt) {
    const u16* qp = Q + (((size_t)bh << 10) + qrow0 + qt * 16 + l16) * 64 + quad * 8;
    qf[qt][0] = *(const bf16x8*)(qp);
    qf[qt][1] = *(const bf16x8*)(qp + 32);
  }

  // ---- stage rel-pos tables (fp32 -> bf16, x8 scale, log2 domain) ----
  for (int j = tid; j < 64 * 8; j += 256) {
    const int row = j >> 3, ck = (j & 7) << 3;
    uint4 vw;
    if (row < 63) cvt8s(rpw + (size_t)row * 64 + ck, &vw, RPSCALE);
    else { vw.x = 0u; vw.y = 0u; vw.z = 0u; vw.w = 0u; }
    *(uint4*)(uRPW + row * 72 + ck) = vw;
    if (row < 63) {
      uint4 vh;
      cvt8s(rph + (size_t)row * 64 + ck, &vh, RPSCALE);
      *(uint4*)(uRPH + row * 72 + ck) = vh;
    }
  }
  __syncthreads();

  // ---- Sh[q][kh] = Qs·rp8h[qh+31-kh] -> sShw (32 x 36) ----
  #pragma unroll
  for (int qt = 0; qt < 2; ++qt)
    #pragma unroll
    for (int tk = 0; tk < 2; ++tk) {
      const int kh = tk * 16 + l16;
      const u16* bp = uRPH + (qh + 31 - kh) * 72 + quad * 8;
      bf16x8 b0 = *(const bf16x8*)(bp);
      bf16x8 b1 = *(const bf16x8*)(bp + 32);
      f32x4 c; c[0] = 0.f; c[1] = 0.f; c[2] = 0.f; c[3] = 0.f;
      c = MFMA(qf[qt][0], b0, c);
      c = MFMA(qf[qt][1], b1, c);
      #pragma unroll
      for (int r = 0; r < 4; ++r)
        sShw[(qt * 16 + quad * 4 + r) * 36 + tk * 16 + l16] = f2bf(c[r]);
    }

  // ---- Sw[q][j] = Qs·rp8w[j]; held in regs until barrier ----
  f32x4 swc[2][4];
  #pragma unroll
  for (int qt = 0; qt < 2; ++qt)
    #pragma unroll
    for (int tj = 0; tj < 4; ++tj) {
      const u16* bp = uRPW + (tj * 16 + l16) * 72 + quad * 8;
      bf16x8 b0 = *(const bf16x8*)(bp);
      bf16x8 b1 = *(const bf16x8*)(bp + 32);
      f32x4 c; c[0] = 0.f; c[1] = 0.f; c[2] = 0.f; c[3] = 0.f;
      c = MFMA(qf[qt][0], b0, c);
      c = MFMA(qf[qt][1], b1, c);
      swc[qt][tj] = c;
    }
  __syncthreads();   // all uRPH/uRPW reads complete before pw overwrites

  #pragma unroll
  for (int qt = 0; qt < 2; ++qt)
    #pragma unroll
    for (int tj = 0; tj < 4; ++tj)
      #pragma unroll
      for (int r = 0; r < 4; ++r)
        pw[(qt * 16 + quad * 4 + r) * 72 + tj * 16 + l16] = f2bf(swc[qt][tj][r]);

  // gather rel_w[qw][kw] = Sw[q][qw-kw+31] (wave-private, in-order RAW)
  float rw[2][2][4];
  #pragma unroll
  for (int qt = 0; qt < 2; ++qt)
    #pragma unroll
    for (int hi = 0; hi < 2; ++hi)
      #pragma unroll
      for (int r = 0; r < 4; ++r) {
        const int kw = hi * 16 + quad * 4 + r;
        rw[qt][hi][r] = bf2f(pw[(qt * 16 + l16) * 72 + (qt * 16 + l16 - kw + 31)]);
      }

  f32x4 oacc[2][4];
  #pragma unroll
  for (int qt = 0; qt < 2; ++qt)
    #pragma unroll
    for (int nd = 0; nd < 4; ++nd) {
      oacc[qt][nd][0] = 0.f; oacc[qt][nd][1] = 0.f;
      oacc[qt][nd][2] = 0.f; oacc[qt][nd][3] = 0.f;
    }
  float lsum[2] = {0.f, 0.f};

  const u16* const Kfb = Kf + (((size_t)bh) << 16) + lane * 8;
  const u16* const Vfb = Vf + (((size_t)bh) << 16) + lane * 8;

  for (int kt = 0; kt < 16; ++kt) {
    const u16* Kp = Kfb + ((size_t)kt << 12);
    const u16* Vp = Vfb + ((size_t)kt << 12);
    bf16x8 kfr[8];
    #pragma unroll
    for (int m = 0; m < 8; ++m)
      kfr[m] = *(const bf16x8*)(Kp + (m << 9));
    #pragma unroll
    for (int m = 0; m < 8; ++m)
      asm volatile("" :: "v"(kfr[m]));

    float rh[2][2];
    #pragma unroll
    for (int qt = 0; qt < 2; ++qt) {
      const unsigned int w2 =
          *(const unsigned int*)(sShw + (qt * 16 + l16) * 36 + (kt << 1));
      rh[qt][0] = bf2f((u16)(w2 & 0xffffu));
      rh[qt][1] = bf2f((u16)(w2 >> 16));
    }

    #pragma unroll
    for (int qt = 0; qt < 2; ++qt) {
      f32x4 sacc[4];
      #pragma unroll
      for (int mk = 0; mk < 4; ++mk) {
        f32x4 t4; t4[0] = 0.f; t4[1] = 0.f; t4[2] = 0.f; t4[3] = 0.f;
        t4 = MFMA(kfr[mk * 2 + 0], qf[qt][0], t4);
        t4 = MFMA(kfr[mk * 2 + 1], qf[qt][1], t4);
        sacc[mk] = t4;
      }
      #pragma unroll
      for (int mk = 0; mk < 4; ++mk) {
        const float rhv = rh[qt][mk >> 1];
        const float* rwp = rw[qt][mk & 1];
        float e0 = EXP2(sacc[mk][0] + rhv + rwp[0]);
        float e1 = EXP2(sacc[mk][1] + rhv + rwp[1]);
        float e2 = EXP2(sacc[mk][2] + rhv + rwp[2]);
        float e3 = EXP2(sacc[mk][3] + rhv + rwp[3]);
        lsum[qt] += (e0 + e1) + (e2 + e3);
        uint2 pk2; pk2.x = pk2bf(e0, e1); pk2.y = pk2bf(e2, e3);
        *(uint2*)(pw + (qt * 16 + l16) * 72 + mk * 16 + quad * 4) = pk2;
      }
    }

    #pragma unroll
    for (int ks = 0; ks < 2; ++ks) {
      bf16x8 bv[4];
      #pragma unroll
      for (int nd = 0; nd < 4; ++nd)
        bv[nd] = *(const bf16x8*)(Vp + ((ks * 4 + nd) << 9));
      #pragma unroll
      for (int qt = 0; qt < 2; ++qt) {
        bf16x8 ap = *(const bf16x8*)(pw + (qt * 16 + l16) * 72 + ks * 32 + quad * 8);
        #pragma unroll
        for (int nd = 0; nd < 4; ++nd)
          oacc[qt][nd] = MFMA(bv[nd], ap, oacc[qt][nd]);
      }
    }
  }

  const int b = bh / 12, head = bh - b * 12;
  #pragma unroll
  for (int qt = 0; qt < 2; ++qt) {
    float ls = lsum[qt];
    ls += __shfl_xor(ls, 16);
    ls += __shfl_xor(ls, 32);
    const float linv = 1.0f / ls;
    const size_t base =
        ((size_t)(b << 10) + qrow0 + qt * 16 + l16) * 768 + head * 64 + quad * 4;
    #pragma unroll
    for (int nd = 0; nd < 4; ++nd) {
      s16x4 pk;
      #pragma unroll
      for (int r = 0; r < 4; ++r) pk[r] = (short)f2bf(oacc[qt][nd][r] * linv);
      *(s16x4*)(Oa + base + nd * 16) = pk;
    }
  }
}

// ---------------------------------------------------------------------------
extern "C" void kernel_launch(void* const* d_in, const int* in_sizes, int n_in,
                              void* d_out, int out_size, void* d_ws, size_t ws_size,
                              hipStream_t stream) {
  (void)in_sizes; (void)n_in; (void)out_size; (void)ws_size;
  const float* x      = (const float*)d_in[0];   // (8,32,32,768)
  const float* qkv_w  = (const float*)d_in[1];   // (2304,768)
  const float* qkv_b  = (const float*)d_in[2];   // (2304)
  const float* proj_w = (const float*)d_in[3];   // (768,768)
  const float* proj_b = (const float*)d_in[4];   // (768)
  const float* rph    = (const float*)d_in[5];   // (63,64)
  const float* rpw    = (const float*)d_in[6];   // (63,64)
  float* out = (float*)d_out;

  char* ws = (char*)d_ws;
  const size_t SZ = (size_t)96 * 1024 * 64;     // elems per plane (12 MB)
  u16* Qw  = (u16*)ws;                          // Qs [bh][n][c] bf16 (pre-scaled)
  u16* Kfw = Qw + SZ;                           // K  fragment-linear bf16
  u16* Vfw = Kfw + SZ;                          // V  fragment-linear bf16
  u16* Xb  = Vfw + SZ;                          // bf16 x; aliased as Oa after QKV GEMM
  u16* Oa  = Xb;                                //   (x dead once QKV GEMM completes)
  u16* QWb = Xb + SZ;                           // bf16 qkv_w (2304x768)
  u16* PWb = QWb + (size_t)2304 * 768;          // bf16 proj_w (768x768)  -> ~55 MB total

  cast_kernel<<<4224, 256, 0, stream>>>(x, qkv_w, proj_w, Xb, QWb, PWb);
  // QKV: BM=128, BN=192 (NJ=6), grid 64x12 = 768 = exactly 3 blocks/CU
  gemm_bt<1, 12, 6><<<768, 256, 0, stream>>>(Xb, QWb, qkv_b, Qw, Kfw, Vfw, 8192, 2304, 768);
  attn_kernel<<<768, 256, 0, stream>>>(Qw, Kfw, Vfw, rph, rpw, Oa);
  // proj: BM=128, BN=96 (NJ=3), grid 64x8 = 512 = 2 blocks/CU exact (zero tail)
  gemm_bt<0, 8, 3><<<512, 256, 0, stream>>>(Oa, PWb, proj_b, out, nullptr, nullptr, 8192, 768, 768);
}